// Round 1
// baseline (503.377 us; speedup 1.0000x reference)
//
#include <hip/hip_runtime.h>
#include <math.h>

// Shapes (fixed by the problem)
#define B_  32
#define T_  768
#define C_  448
#define E_  256
#define N_  3136   // 56*56
#define N4_ 784    // N_/4
#define CCHUNK_ 16
#define CPER_   28 // C_/CCHUNK_
#define TOTAL4_ 11239424  // B_*C_*N_/4 == 43904*256

// ---------------- Kernel 1: q = text@q_w^T + q_b ; qk = scale * k_w^T q ----
__global__ __launch_bounds__(256) void k1_qk(
    const float* __restrict__ text, const float* __restrict__ q_w,
    const float* __restrict__ q_b,  const float* __restrict__ k_w,
    float* __restrict__ qk)
{
    const int b = blockIdx.x, tid = threadIdx.x;
    __shared__ float t_lds[T_];
    __shared__ float q_lds[E_];
    for (int i = tid; i < T_; i += 256) t_lds[i] = text[b * T_ + i];
    __syncthreads();
    {   // each thread computes one q[e]
        const int e = tid;
        float acc = q_b[e];
        const float* qw = q_w + (size_t)e * T_;
        #pragma unroll 4
        for (int t = 0; t < T_; ++t) acc = fmaf(t_lds[t], qw[t], acc);
        q_lds[e] = acc;
    }
    __syncthreads();
    const float scale = 0.0625f;  // 1/sqrt(E_)
    for (int c = tid; c < C_; c += 256) {
        float acc = 0.f;
        for (int e = 0; e < E_; ++e) acc = fmaf(q_lds[e], k_w[e * C_ + c], acc);
        qk[b * C_ + c] = acc * scale;
    }
}

// ---------------- Kernel 2: partial logits over a 28-channel chunk ---------
// partial[cy][b][n] = sum_{c in chunk cy} qk[b,c] * img[b,c,n]
__global__ __launch_bounds__(256) void k2_logits(
    const float* __restrict__ img, const float* __restrict__ qk,
    float* __restrict__ partial)
{
    const int cy = blockIdx.x;          // 0..15
    const int b  = blockIdx.y;          // 0..31
    const int tid = threadIdx.x;
    const int c0 = cy * CPER_;

    __shared__ float w_lds[CPER_];
    if (tid < CPER_) w_lds[tid] = qk[b * C_ + c0 + tid];
    __syncthreads();

    float4 a0 = {0.f,0.f,0.f,0.f}, a1 = {0.f,0.f,0.f,0.f};
    float4 a2 = {0.f,0.f,0.f,0.f}, a3 = {0.f,0.f,0.f,0.f};
    const float4* imgb = (const float4*)img + (size_t)(b * C_ + c0) * N4_;
    const bool tail = (tid < (N4_ - 768));  // 784-768 = 16 lanes

    for (int c = 0; c < CPER_; ++c) {
        const float w = w_lds[c];
        const float4* row = imgb + (size_t)c * N4_;
        float4 x0 = row[tid];
        float4 x1 = row[tid + 256];
        float4 x2 = row[tid + 512];
        a0.x = fmaf(w, x0.x, a0.x); a0.y = fmaf(w, x0.y, a0.y);
        a0.z = fmaf(w, x0.z, a0.z); a0.w = fmaf(w, x0.w, a0.w);
        a1.x = fmaf(w, x1.x, a1.x); a1.y = fmaf(w, x1.y, a1.y);
        a1.z = fmaf(w, x1.z, a1.z); a1.w = fmaf(w, x1.w, a1.w);
        a2.x = fmaf(w, x2.x, a2.x); a2.y = fmaf(w, x2.y, a2.y);
        a2.z = fmaf(w, x2.z, a2.z); a2.w = fmaf(w, x2.w, a2.w);
        if (tail) {
            float4 x3 = row[tid + 768];
            a3.x = fmaf(w, x3.x, a3.x); a3.y = fmaf(w, x3.y, a3.y);
            a3.z = fmaf(w, x3.z, a3.z); a3.w = fmaf(w, x3.w, a3.w);
        }
    }
    float4* p = (float4*)partial + (size_t)(cy * B_ + b) * N4_;
    p[tid]       = a0;
    p[tid + 256] = a1;
    p[tid + 512] = a2;
    if (tail) p[tid + 768] = a3;
}

// ---------------- Kernel 3: reduce partials + softmax over N ---------------
__global__ __launch_bounds__(256) void k3_softmax(
    const float* __restrict__ partial, float* __restrict__ attn)
{
    const int b = blockIdx.x, tid = threadIdx.x;
    __shared__ float4 l4[N4_];          // 12.25 KB
    __shared__ float redm[4];
    __shared__ float reds[4];

    float lmax = -1e30f;
    for (int i4 = tid; i4 < N4_; i4 += 256) {
        float4 s = {0.f,0.f,0.f,0.f};
        for (int cy = 0; cy < CCHUNK_; ++cy) {
            const float4 p = ((const float4*)partial)[(size_t)(cy * B_ + b) * N4_ + i4];
            s.x += p.x; s.y += p.y; s.z += p.z; s.w += p.w;
        }
        l4[i4] = s;
        lmax = fmaxf(lmax, fmaxf(fmaxf(s.x, s.y), fmaxf(s.z, s.w)));
    }
    // block max reduce (4 waves)
    for (int off = 32; off; off >>= 1) lmax = fmaxf(lmax, __shfl_down(lmax, off));
    if ((tid & 63) == 0) redm[tid >> 6] = lmax;
    __syncthreads();
    const float m = fmaxf(fmaxf(redm[0], redm[1]), fmaxf(redm[2], redm[3]));

    float lsum = 0.f;
    for (int i4 = tid; i4 < N4_; i4 += 256) {
        float4 v = l4[i4];
        v.x = expf(v.x - m); v.y = expf(v.y - m);
        v.z = expf(v.z - m); v.w = expf(v.w - m);
        l4[i4] = v;
        lsum += v.x + v.y + v.z + v.w;
    }
    for (int off = 32; off; off >>= 1) lsum += __shfl_down(lsum, off);
    if ((tid & 63) == 0) reds[tid >> 6] = lsum;
    __syncthreads();
    const float inv = 1.f / (reds[0] + reds[1] + reds[2] + reds[3]);

    for (int i4 = tid; i4 < N4_; i4 += 256) {
        float4 v = l4[i4];
        v.x *= inv; v.y *= inv; v.z *= inv; v.w *= inv;
        ((float4*)attn)[(size_t)b * N4_ + i4] = v;
    }
}

// ---------------- Kernel 4: pooled_img[b,c] = sum_n attn[b,n]*img[b,c,n] ---
__global__ __launch_bounds__(64) void k4_pool(
    const float* __restrict__ img, const float* __restrict__ attn,
    float* __restrict__ pimg)
{
    const int c = blockIdx.x, b = blockIdx.y, tid = threadIdx.x;  // 64 threads
    const float4* row = (const float4*)img + (size_t)(b * C_ + c) * N4_;
    const float4* at  = (const float4*)attn + (size_t)b * N4_;
    float4 acc = {0.f,0.f,0.f,0.f};
    for (int i4 = tid; i4 < N4_; i4 += 64) {
        const float4 x = row[i4];
        const float4 a = at[i4];
        acc.x = fmaf(a.x, x.x, acc.x); acc.y = fmaf(a.y, x.y, acc.y);
        acc.z = fmaf(a.z, x.z, acc.z); acc.w = fmaf(a.w, x.w, acc.w);
    }
    float s = acc.x + acc.y + acc.z + acc.w;
    for (int off = 32; off; off >>= 1) s += __shfl_down(s, off);
    if (tid == 0) pimg[b * C_ + c] = s;
}

// ---------------- Kernel 5: pooled = v_w@pimg + v_b ; out = o_w@pooled + o_b
__global__ __launch_bounds__(256) void k5_out(
    const float* __restrict__ pimg, const float* __restrict__ v_w,
    const float* __restrict__ v_b,  const float* __restrict__ o_w,
    const float* __restrict__ o_b,  float* __restrict__ outvec)
{
    const int b = blockIdx.x, tid = threadIdx.x;
    __shared__ float p_lds[C_];
    __shared__ float e_lds[E_];
    for (int c = tid; c < C_; c += 256) p_lds[c] = pimg[b * C_ + c];
    __syncthreads();
    {
        const int e = tid;
        float acc = v_b[e];
        const float* vw = v_w + (size_t)e * C_;
        for (int c = 0; c < C_; ++c) acc = fmaf(vw[c], p_lds[c], acc);
        e_lds[e] = acc;
    }
    __syncthreads();
    for (int c = tid; c < C_; c += 256) {
        float acc = o_b[c];
        const float* ow = o_w + (size_t)c * E_;
        for (int e = 0; e < E_; ++e) acc = fmaf(ow[e], e_lds[e], acc);
        outvec[b * C_ + c] = acc;
    }
}

// ---------------- Kernel 6: out = img + outvec[b,c] broadcast --------------
__global__ __launch_bounds__(256) void k6_add(
    const float* __restrict__ img, const float* __restrict__ outvec,
    float* __restrict__ out)
{
    const unsigned i = blockIdx.x * 256u + threadIdx.x;   // < TOTAL4_
    const float4 x = ((const float4*)img)[i];
    const float o = outvec[i / N4_];   // row = b*C_+c; wave-uniform-ish, cached
    float4 r;
    r.x = x.x + o; r.y = x.y + o; r.z = x.z + o; r.w = x.w + o;
    ((float4*)out)[i] = r;
}

extern "C" void kernel_launch(void* const* d_in, const int* in_sizes, int n_in,
                              void* d_out, int out_size, void* d_ws, size_t ws_size,
                              hipStream_t stream) {
    const float* text = (const float*)d_in[0];
    const float* img  = (const float*)d_in[1];
    const float* q_w  = (const float*)d_in[2];
    const float* q_b  = (const float*)d_in[3];
    const float* k_w  = (const float*)d_in[4];
    const float* k_b  = (const float*)d_in[5];  // unused: cancels in softmax
    const float* v_w  = (const float*)d_in[6];
    const float* v_b  = (const float*)d_in[7];
    const float* o_w  = (const float*)d_in[8];
    const float* o_b  = (const float*)d_in[9];
    float* out = (float*)d_out;
    (void)k_b; (void)in_sizes; (void)n_in; (void)out_size; (void)ws_size;

    // workspace layout (floats)
    float* ws      = (float*)d_ws;
    float* qk      = ws;                                   // B_*C_      = 14336
    float* partial = qk + B_ * C_;                         // 16*B_*N_   = 802816
    float* attn    = partial + CCHUNK_ * B_ * N_;          // B_*N_      = 100352
    float* pimg    = attn + B_ * N_;                       // B_*C_      = 14336
    float* outvec  = pimg + B_ * C_;                       // B_*C_      = 14336

    k1_qk<<<B_, 256, 0, stream>>>(text, q_w, q_b, k_w, qk);
    k2_logits<<<dim3(CCHUNK_, B_), 256, 0, stream>>>(img, qk, partial);
    k3_softmax<<<B_, 256, 0, stream>>>(partial, attn);
    k4_pool<<<dim3(C_, B_), 64, 0, stream>>>(img, attn, pimg);
    k5_out<<<B_, 256, 0, stream>>>(pimg, v_w, v_b, o_w, o_b, outvec);
    k6_add<<<TOTAL4_ / 256, 256, 0, stream>>>(img, outvec, out);
}